// Round 1
// baseline (553.197 us; speedup 1.0000x reference)
//
#include <hip/hip_runtime.h>

#define F_IN  64
#define F_OUT 64
#define KF    256   // K * F_OUT

// ---------------------------------------------------------------------------
// Kernel 1: per-feature sum and sum-of-squares (for BatchNorm batch stats).
// Block = 256 threads = 4 rows x 64 features; grid-stride over rows.
// Partial reduce in LDS, one atomicAdd per feature per block.
// ---------------------------------------------------------------------------
__global__ __launch_bounds__(256) void stats_kernel(
    const float* __restrict__ a, float* __restrict__ stats, int N)
{
    __shared__ float ssum[256];
    __shared__ float ssq[256];
    const int tid = threadIdx.x;
    const int c   = tid & 63;
    int r         = blockIdx.x * 4 + (tid >> 6);
    const int rstride = gridDim.x * 4;
    float ps = 0.f, pq = 0.f;
    for (; r < N; r += rstride) {
        float v = a[(size_t)r * F_IN + c];
        ps += v;
        pq += v * v;
    }
    ssum[tid] = ps;
    ssq[tid]  = pq;
    __syncthreads();
    if (tid < 64) {
        float s = ssum[tid] + ssum[tid + 64] + ssum[tid + 128] + ssum[tid + 192];
        float q = ssq[tid]  + ssq[tid + 64]  + ssq[tid + 128]  + ssq[tid + 192];
        atomicAdd(&stats[tid], s);
        atomicAdd(&stats[64 + tid], q);
    }
}

// ---------------------------------------------------------------------------
// Kernel 2: fused BN -> ELU -> Linear.  xlin[n, t] = elu(bn(a[n,:])) . W[:,t] + b[t]
// Block = 256 threads; each thread owns output column t = tid (W column in
// 64 VGPRs).  32 rows of BN+ELU'd input staged in LDS per block; inner
// 64-FMA loop reads xs via LDS broadcast (wave-uniform address -> free).
// ---------------------------------------------------------------------------
__global__ __launch_bounds__(256) void gemm_kernel(
    const float* __restrict__ a, const float* __restrict__ stats,
    const float* __restrict__ gamma, const float* __restrict__ beta,
    const float* __restrict__ W, const float* __restrict__ b,
    float* __restrict__ xlin, int N)
{
    __shared__ float xs[32][F_IN];
    const int tid = threadIdx.x;
    const int c   = tid & 63;

    // BN params for feature c (biased variance, matching jnp.var)
    const float invN  = 1.0f / (float)N;
    const float mean  = stats[c] * invN;
    const float var   = stats[64 + c] * invN - mean * mean;
    const float scale = rsqrtf(var + 1e-5f) * gamma[c];
    const float shift = beta[c];

    // W column t=tid into registers (coalesced across threads)
    float wreg[F_IN];
#pragma unroll
    for (int k = 0; k < F_IN; ++k) wreg[k] = W[k * KF + tid];
    const float bias = b[tid];

    const int i0 = blockIdx.x * 32;

    // Stage 32 rows of BN+ELU input into LDS (8 coalesced passes)
#pragma unroll
    for (int it = 0; it < 8; ++it) {
        int idx = tid + it * 256;
        int r   = idx >> 6;
        int row = i0 + r;
        float v = 0.f;
        if (row < N) {
            v = (a[(size_t)row * F_IN + c] - mean) * scale + shift;
            v = (v > 0.f) ? v : expm1f(v);   // ELU, alpha=1
        }
        xs[r][c] = v;
    }
    __syncthreads();

    const int rmax = min(32, N - i0);
    for (int r = 0; r < rmax; ++r) {
        float acc = bias;
#pragma unroll
        for (int k = 0; k < F_IN; ++k)
            acc = fmaf(xs[r][k], wreg[k], acc);
        xlin[(size_t)(i0 + r) * KF + tid] = acc;   // coalesced 1KB store
    }
}

// ---------------------------------------------------------------------------
// Kernel 3: sparse scatter.  One 64-lane group per edge; lane = feature.
// stacked[col, f] == xlin[col % N, (col / N) * 64 + f]  (transpose folded
// into the index math, so the [K*N, F] transpose is never materialized).
// ---------------------------------------------------------------------------
__global__ __launch_bounds__(256) void scatter_kernel(
    const float* __restrict__ vals, const int* __restrict__ rows,
    const int* __restrict__ cols, const float* __restrict__ xlin,
    float* __restrict__ out, int N, int E)
{
    const int lane = threadIdx.x & 63;
    int e = blockIdx.x * 4 + (threadIdx.x >> 6);
    const int estride = gridDim.x * 4;
    for (; e < E; e += estride) {
        float v  = vals[e];
        int   r  = rows[e];
        int   cc = cols[e];
        // k = cc / N, n2 = cc % N  (K is tiny: <=3 subtractions, wave-uniform)
        int k = 0, n2 = cc;
        while (n2 >= N) { n2 -= N; ++k; }
        float x = xlin[(size_t)n2 * KF + k * F_OUT + lane];  // coalesced 256B gather
        atomicAdd(&out[(size_t)r * F_OUT + lane], v * x);    // coalesced 256B atomic
    }
}

extern "C" void kernel_launch(void* const* d_in, const int* in_sizes, int n_in,
                              void* d_out, int out_size, void* d_ws, size_t ws_size,
                              hipStream_t stream)
{
    const float* a     = (const float*)d_in[0];
    const float* gamma = (const float*)d_in[1];
    const float* beta  = (const float*)d_in[2];
    const float* W     = (const float*)d_in[3];
    const float* b     = (const float*)d_in[4];
    const float* vals  = (const float*)d_in[5];
    const int*   rows  = (const int*)d_in[6];
    const int*   cols  = (const int*)d_in[7];
    float*       out   = (float*)d_out;

    const int N = in_sizes[0] / F_IN;
    const int E = in_sizes[5];

    float* stats = (float*)d_ws;                      // 128 floats (sum, sumsq)
    float* xlin  = (float*)((char*)d_ws + 1024);      // [N, 256] f32 = 102.4 MB

    // Zero accumulators every call (harness poisons once, replays many times)
    hipMemsetAsync(d_ws, 0, 512, stream);
    hipMemsetAsync(d_out, 0, (size_t)out_size * sizeof(float), stream);

    stats_kernel<<<512, 256, 0, stream>>>(a, stats, N);
    gemm_kernel<<<(N + 31) / 32, 256, 0, stream>>>(a, stats, gamma, beta, W, b, xlin, N);
    scatter_kernel<<<8192, 256, 0, stream>>>(vals, rows, cols, xlin, out, N, E);
}

// Round 2
// 492.516 us; speedup vs baseline: 1.1232x; 1.1232x over previous
//
#include <hip/hip_runtime.h>

#define F_IN  64
#define F_OUT 64
#define KF    256   // K * F_OUT
#define TILE  1024  // scan tile (256 threads x 4 elems)

// ---------------------------------------------------------------------------
// Kernel 1: per-feature sum and sum-of-squares (BatchNorm batch stats).
// ---------------------------------------------------------------------------
__global__ __launch_bounds__(256) void stats_kernel(
    const float* __restrict__ a, float* __restrict__ stats, int N)
{
    __shared__ float ssum[256];
    __shared__ float ssq[256];
    const int tid = threadIdx.x;
    const int c   = tid & 63;
    int r         = blockIdx.x * 4 + (tid >> 6);
    const int rstride = gridDim.x * 4;
    float ps = 0.f, pq = 0.f;
    for (; r < N; r += rstride) {
        float v = a[(size_t)r * F_IN + c];
        ps += v;
        pq += v * v;
    }
    ssum[tid] = ps;
    ssq[tid]  = pq;
    __syncthreads();
    if (tid < 64) {
        float s = ssum[tid] + ssum[tid + 64] + ssum[tid + 128] + ssum[tid + 192];
        float q = ssq[tid]  + ssq[tid + 64]  + ssq[tid + 128]  + ssq[tid + 192];
        atomicAdd(&stats[tid], s);
        atomicAdd(&stats[64 + tid], q);
    }
}

// ---------------------------------------------------------------------------
// Kernel 2: fused BN -> ELU -> Linear (unchanged this round).
// ---------------------------------------------------------------------------
__global__ __launch_bounds__(256) void gemm_kernel(
    const float* __restrict__ a, const float* __restrict__ stats,
    const float* __restrict__ gamma, const float* __restrict__ beta,
    const float* __restrict__ W, const float* __restrict__ b,
    float* __restrict__ xlin, int N)
{
    __shared__ float xs[32][F_IN];
    const int tid = threadIdx.x;
    const int c   = tid & 63;

    const float invN  = 1.0f / (float)N;
    const float mean  = stats[c] * invN;
    const float var   = stats[64 + c] * invN - mean * mean;
    const float scale = rsqrtf(var + 1e-5f) * gamma[c];
    const float shift = beta[c];

    float wreg[F_IN];
#pragma unroll
    for (int k = 0; k < F_IN; ++k) wreg[k] = W[k * KF + tid];
    const float bias = b[tid];

    const int i0 = blockIdx.x * 32;

#pragma unroll
    for (int it = 0; it < 8; ++it) {
        int idx = tid + it * 256;
        int r   = idx >> 6;
        int row = i0 + r;
        float v = 0.f;
        if (row < N) {
            v = (a[(size_t)row * F_IN + c] - mean) * scale + shift;
            v = (v > 0.f) ? v : expm1f(v);
        }
        xs[r][c] = v;
    }
    __syncthreads();

    const int rmax = min(32, N - i0);
    for (int r = 0; r < rmax; ++r) {
        float acc = bias;
#pragma unroll
        for (int k = 0; k < F_IN; ++k)
            acc = fmaf(xs[r][k], wreg[k], acc);
        xlin[(size_t)(i0 + r) * KF + tid] = acc;
    }
}

// ---------------------------------------------------------------------------
// CSR build: histogram -> 3-kernel exclusive scan -> fill (bucket sort).
// ---------------------------------------------------------------------------
__global__ __launch_bounds__(256) void hist_kernel(
    const int* __restrict__ rows, int* __restrict__ counts, int E)
{
    int e = blockIdx.x * 256 + threadIdx.x;
    if (e < E) atomicAdd(&counts[rows[e]], 1);
}

__global__ __launch_bounds__(256) void scanA_kernel(
    const int* __restrict__ counts, int* __restrict__ offsets,
    int* __restrict__ bsum, int N)
{
    __shared__ int s[256];
    const int tid  = threadIdx.x;
    const int base = blockIdx.x * TILE + tid * 4;
    int v0 = 0, v1 = 0, v2 = 0, v3 = 0;
    if (base + 3 < N) {
        int4 q = *(const int4*)(counts + base);
        v0 = q.x; v1 = q.y; v2 = q.z; v3 = q.w;
    } else {
        if (base + 0 < N) v0 = counts[base + 0];
        if (base + 1 < N) v1 = counts[base + 1];
        if (base + 2 < N) v2 = counts[base + 2];
        if (base + 3 < N) v3 = counts[base + 3];
    }
    const int tsum = v0 + v1 + v2 + v3;
    s[tid] = tsum;
    __syncthreads();
    // Hillis-Steele inclusive scan over 256 thread sums
    for (int off = 1; off < 256; off <<= 1) {
        int t = (tid >= off) ? s[tid - off] : 0;
        __syncthreads();
        s[tid] += t;
        __syncthreads();
    }
    const int excl = s[tid] - tsum;   // exclusive prefix of this thread
    int e0 = excl, e1 = e0 + v0, e2 = e1 + v1, e3 = e2 + v2;
    if (base + 0 < N) offsets[base + 0] = e0;
    if (base + 1 < N) offsets[base + 1] = e1;
    if (base + 2 < N) offsets[base + 2] = e2;
    if (base + 3 < N) offsets[base + 3] = e3;
    if (tid == 255) bsum[blockIdx.x] = s[255];
}

__global__ __launch_bounds__(256) void scanB_kernel(int* __restrict__ bsum, int NB)
{
    __shared__ int s[256];
    const int tid = threadIdx.x;
    const int v   = (tid < NB) ? bsum[tid] : 0;
    s[tid] = v;
    __syncthreads();
    for (int off = 1; off < 256; off <<= 1) {
        int t = (tid >= off) ? s[tid - off] : 0;
        __syncthreads();
        s[tid] += t;
        __syncthreads();
    }
    if (tid < NB) bsum[tid] = s[tid] - v;   // exclusive
}

__global__ __launch_bounds__(256) void scanC_kernel(
    int* __restrict__ offsets, const int* __restrict__ bsum, int N)
{
    const int add  = bsum[blockIdx.x];
    const int base = blockIdx.x * TILE + threadIdx.x * 4;
#pragma unroll
    for (int i = 0; i < 4; ++i)
        if (base + i < N) offsets[base + i] += add;
}

__global__ __launch_bounds__(256) void fill_kernel(
    const float* __restrict__ vals, const int* __restrict__ rows,
    const int* __restrict__ cols, int* __restrict__ offsets,
    int2* __restrict__ sorted, int E)
{
    int e = blockIdx.x * 256 + threadIdx.x;
    if (e >= E) return;
    const int r   = rows[e];
    const int pos = atomicAdd(&offsets[r], 1);    // offsets -> inclusive ends
    sorted[pos]   = make_int2(cols[e], __float_as_int(vals[e]));
}

// ---------------------------------------------------------------------------
// Accumulate: one wave per output row, lane = feature. No atomics; out
// written exactly once.  beg = end - counts[r] (counts left intact by fill).
// ---------------------------------------------------------------------------
__global__ __launch_bounds__(256) void accum_kernel(
    const int2* __restrict__ sorted, const int* __restrict__ counts,
    const int* __restrict__ offsets, const float* __restrict__ xlin,
    float* __restrict__ out, int N)
{
    const int lane = threadIdx.x & 63;
    const int r    = blockIdx.x * 4 + (threadIdx.x >> 6);
    if (r >= N) return;
    const int end = offsets[r];
    int i         = end - counts[r];
    float acc = 0.f;
    for (; i + 1 < end; i += 2) {
        const int2 a = sorted[i];
        const int2 b = sorted[i + 1];
        int k0 = 0, n0 = a.x; while (n0 >= N) { n0 -= N; ++k0; }
        int k1 = 0, n1 = b.x; while (n1 >= N) { n1 -= N; ++k1; }
        const float x0 = xlin[(size_t)n0 * KF + k0 * F_OUT + lane];
        const float x1 = xlin[(size_t)n1 * KF + k1 * F_OUT + lane];
        acc = fmaf(__int_as_float(a.y), x0, acc);
        acc = fmaf(__int_as_float(b.y), x1, acc);
    }
    if (i < end) {
        const int2 a = sorted[i];
        int k0 = 0, n0 = a.x; while (n0 >= N) { n0 -= N; ++k0; }
        acc = fmaf(__int_as_float(a.y), xlin[(size_t)n0 * KF + k0 * F_OUT + lane], acc);
    }
    out[(size_t)r * F_OUT + lane] = acc;
}

// ---------------------------------------------------------------------------
// Fallback scatter (round-1 passing path) if workspace is too small for CSR.
// ---------------------------------------------------------------------------
__global__ __launch_bounds__(256) void scatter_kernel(
    const float* __restrict__ vals, const int* __restrict__ rows,
    const int* __restrict__ cols, const float* __restrict__ xlin,
    float* __restrict__ out, int N, int E)
{
    const int lane = threadIdx.x & 63;
    int e = blockIdx.x * 4 + (threadIdx.x >> 6);
    const int estride = gridDim.x * 4;
    for (; e < E; e += estride) {
        float v  = vals[e];
        int   r  = rows[e];
        int   cc = cols[e];
        int k = 0, n2 = cc;
        while (n2 >= N) { n2 -= N; ++k; }
        float x = xlin[(size_t)n2 * KF + k * F_OUT + lane];
        atomicAdd(&out[(size_t)r * F_OUT + lane], v * x);
    }
}

extern "C" void kernel_launch(void* const* d_in, const int* in_sizes, int n_in,
                              void* d_out, int out_size, void* d_ws, size_t ws_size,
                              hipStream_t stream)
{
    const float* a     = (const float*)d_in[0];
    const float* gamma = (const float*)d_in[1];
    const float* beta  = (const float*)d_in[2];
    const float* W     = (const float*)d_in[3];
    const float* b     = (const float*)d_in[4];
    const float* vals  = (const float*)d_in[5];
    const int*   rows  = (const int*)d_in[6];
    const int*   cols  = (const int*)d_in[7];
    float*       out   = (float*)d_out;

    const int N  = in_sizes[0] / F_IN;
    const int E  = in_sizes[5];
    const int NB = (N + TILE - 1) / TILE;   // scan tiles (98 for N=100000)

    // Workspace layout (all 16B-aligned):
    //   [0,      1024)               stats (128 f32 used)
    //   [1024,   1024+4N)            counts
    //   [.. ,    .. +4N)             offsets
    //   [.. ,    .. +1024)           bsum
    //   [.. ,    .. +8E)             sorted (int2: col, val bits)
    //   [.. ,    .. +4*N*KF)         xlin
    char*  base     = (char*)d_ws;
    size_t o_counts = 1024;
    size_t o_off    = o_counts + (size_t)N * 4;
    size_t o_bsum   = o_off + (size_t)N * 4;
    size_t o_sorted = (o_bsum + 1024 + 15) & ~(size_t)15;
    size_t o_xlin   = (o_sorted + (size_t)E * 8 + 15) & ~(size_t)15;
    size_t need     = o_xlin + (size_t)N * KF * 4;

    const bool use_csr = (ws_size >= need) && (NB <= 256);

    float* stats = (float*)base;
    hipMemsetAsync(d_ws, 0, 512, stream);

    if (use_csr) {
        int*   counts  = (int*)(base + o_counts);
        int*   offsets = (int*)(base + o_off);
        int*   bsum    = (int*)(base + o_bsum);
        int2*  sorted  = (int2*)(base + o_sorted);
        float* xlin    = (float*)(base + o_xlin);

        hipMemsetAsync(counts, 0, (size_t)N * 4, stream);

        stats_kernel<<<512, 256, 0, stream>>>(a, stats, N);
        gemm_kernel<<<(N + 31) / 32, 256, 0, stream>>>(a, stats, gamma, beta, W, b, xlin, N);

        hist_kernel<<<(E + 255) / 256, 256, 0, stream>>>(rows, counts, E);
        scanA_kernel<<<NB, 256, 0, stream>>>(counts, offsets, bsum, N);
        scanB_kernel<<<1, 256, 0, stream>>>(bsum, NB);
        scanC_kernel<<<NB, 256, 0, stream>>>(offsets, bsum, N);
        fill_kernel<<<(E + 255) / 256, 256, 0, stream>>>(vals, rows, cols, offsets, sorted, E);

        accum_kernel<<<(N + 3) / 4, 256, 0, stream>>>(sorted, counts, offsets, xlin, out, N);
    } else {
        float* xlin = (float*)(base + 1024);
        hipMemsetAsync(d_out, 0, (size_t)out_size * sizeof(float), stream);
        stats_kernel<<<512, 256, 0, stream>>>(a, stats, N);
        gemm_kernel<<<(N + 31) / 32, 256, 0, stream>>>(a, stats, gamma, beta, W, b, xlin, N);
        scatter_kernel<<<8192, 256, 0, stream>>>(vals, rows, cols, xlin, out, N, E);
    }
}